// Round 4
// baseline (912.005 us; speedup 1.0000x reference)
//
#include <hip/hip_runtime.h>
#include <stdint.h>

#define N_TOT 32768
#define DDIM  512
#define KCB   8192
#define NSPLIT 4
#define COLS_SPLIT (KCB / NSPLIT)   // 2048
#define BN 128
#define BC 128
#define BKD 64                      // d-chunk depth in halfs
#define NTILES (COLS_SPLIT / BC)    // 16
#define NSTEPS (NTILES * 8)         // 128 flattened (tile, d0) steps
#define MARGIN 0.15f

// batched repair: 32 flagged rows share one codebook stream
#define RB3 32                      // flagged rows per batch (LDS-staged)
#define RP3 32                      // codebook parts (256 rows each, 1 row/thread)
#define RSLOTS (RGRID3 / RP3)       // batch slots in flight
#define RGRID3 2048

typedef _Float16 half8 __attribute__((ext_vector_type(8)));
typedef float    floatx4 __attribute__((ext_vector_type(4)));

// ---------------- async global->LDS 16B ----------------
typedef const __attribute__((address_space(1))) unsigned int* gas_ptr;
typedef __attribute__((address_space(3))) unsigned int* las_ptr;
__device__ __forceinline__ void gld_lds16(void* l, const void* g) {
    __builtin_amdgcn_global_load_lds((gas_ptr)g, (las_ptr)l, 16, 0, 0);
}

__device__ __forceinline__ unsigned long long shfl_xor_u64(unsigned long long v, int m) {
    unsigned int lo = (unsigned int)v, hi = (unsigned int)(v >> 32);
    lo = __shfl_xor(lo, m, 64);
    hi = __shfl_xor(hi, m, 64);
    return ((unsigned long long)hi << 32) | lo;
}

// ---------------- convert x to fp16 ----------------
__global__ __launch_bounds__(256) void convert_x_kernel(
    const float* __restrict__ x, _Float16* __restrict__ xh) {
    size_t i = ((size_t)blockIdx.x * 256 + threadIdx.x) * 8;
    float4 v0 = *(const float4*)(x + i);
    float4 v1 = *(const float4*)(x + i + 4);
    half8 h;
    h[0] = (_Float16)v0.x; h[1] = (_Float16)v0.y; h[2] = (_Float16)v0.z; h[3] = (_Float16)v0.w;
    h[4] = (_Float16)v1.x; h[5] = (_Float16)v1.y; h[6] = (_Float16)v1.z; h[7] = (_Float16)v1.w;
    *(half8*)(xh + i) = h;
}

// ---------------- convert codebook to fp16 + fp32 norms (one wave/row) ----------------
__global__ __launch_bounds__(256) void convert_cb_kernel(
    const float* __restrict__ cb, _Float16* __restrict__ cbh, float* __restrict__ cnorm) {
    int row = blockIdx.x * 4 + (threadIdx.x >> 6);
    int lane = threadIdx.x & 63;
    const float* src = cb + (size_t)row * DDIM + lane * 8;
    float4 v0 = *(const float4*)src;
    float4 v1 = *(const float4*)(src + 4);
    half8 h;
    h[0] = (_Float16)v0.x; h[1] = (_Float16)v0.y; h[2] = (_Float16)v0.z; h[3] = (_Float16)v0.w;
    h[4] = (_Float16)v1.x; h[5] = (_Float16)v1.y; h[6] = (_Float16)v1.z; h[7] = (_Float16)v1.w;
    *(half8*)(cbh + (size_t)row * DDIM + lane * 8) = h;
    float s = v0.x*v0.x + v0.y*v0.y + v0.z*v0.z + v0.w*v0.w
            + v1.x*v1.x + v1.y*v1.y + v1.z*v1.z + v1.w*v1.w;
#pragma unroll
    for (int off = 32; off > 0; off >>= 1) s += __shfl_down(s, off, 64);
    if (lane == 0) cnorm[row] = s;
}

// ---------------- fused fp16 MFMA GEMM + per-row top-2 argmin (K-split) ----------------
// Double-buffered single-barrier pipeline; all addressing hoisted to registers:
//  - staging: saddr-form global_load_lds (uniform SGPR base+offset, invariant VGPR voff)
//  - LDS reads: 16 precomputed swizzled byte addresses, ^=32768 buffer toggle
__global__ __launch_bounds__(256, 2) void gemm_argmin_kernel(
    const _Float16* __restrict__ xh, const _Float16* __restrict__ cbh,
    const float* __restrict__ cnorm,
    float* __restrict__ sb1, int* __restrict__ si1, float* __restrict__ sb2) {

    __shared__ __align__(16) _Float16 smem[32768];  // 64 KiB: 2 x (As[128][64] + Bs[128][64])
    char* smemb = (char*)smem;

    const int tid = threadIdx.x;
    const int wave = tid >> 6;
    const int lane = tid & 63;
    const int rowHalf = wave >> 1;
    const int colHalf = wave & 1;
    const int l15 = lane & 15;
    const int quad = lane >> 4;

    // bijective XCD swizzle (1024 blocks, 1024 % 8 == 0)
    const int orig = blockIdx.x;
    const int wg = ((orig & 7) << 7) | (orig >> 3);
    const int bx = wg & 255;
    const int by = wg >> 8;
    const int row0 = bx * BN;
    const int colBase = by * COLS_SPLIT;

    // ---- step-invariant per-lane staging offsets (halfs) ----
    int voff[4];
#pragma unroll
    for (int r = 0; r < 4; ++r) {
        int c = wave * 256 + r * 64 + lane;
        int ar = c >> 3;
        int q  = (c & 7) ^ (ar & 7);      // XOR swizzle: conflict-free frag reads
        voff[r] = (ar << 9) + q * 8;
    }
    const _Float16* aptr = xh + ((size_t)row0 << 9);      // wave-uniform base
    const _Float16* bptr = cbh + ((size_t)colBase << 9);  // wave-uniform base

    // ---- step-invariant swizzled LDS read byte-addresses (par=0) ----
    int aaddr[2][4], baddr[2][4];
#pragma unroll
    for (int kh = 0; kh < 2; ++kh) {
#pragma unroll
        for (int i = 0; i < 4; ++i) {
            int rr = rowHalf * 64 + i * 16 + l15;
            int qa = (kh * 4 + quad) ^ (rr & 7);
            aaddr[kh][i] = (rr * 64 + qa * 8) * 2;
            int cc = colHalf * 64 + i * 16 + l15;
            int qb = (kh * 4 + quad) ^ (cc & 7);
            baddr[kh][i] = 16384 + (cc * 64 + qb * 8) * 2;
        }
    }

    float b1[16], b2[16];
    int   i1[16];
#pragma unroll
    for (int s = 0; s < 16; ++s) { b1[s] = 3.402823466e38f; b2[s] = 3.402823466e38f; i1[s] = 0; }

#define STAGE(parv, boffu, d0v) do {                                            \
        _Float16* Asb = smem + (parv) * 16384;                                  \
        _Float16* Bsb = Asb + 8192;                                             \
        _Pragma("unroll")                                                       \
        for (int r = 0; r < 4; ++r) {                                           \
            gld_lds16(Asb + (wave * 256 + r * 64) * 8,                          \
                      aptr + (d0v) + voff[r]);                                  \
            gld_lds16(Bsb + (wave * 256 + r * 64) * 8,                          \
                      bptr + (boffu) + (d0v) + voff[r]);                        \
        }                                                                       \
    } while (0)

    floatx4 acc[4][4];
#pragma unroll
    for (int i = 0; i < 4; ++i)
#pragma unroll
        for (int j = 0; j < 4; ++j)
            acc[i][j] = (floatx4){0.f, 0.f, 0.f, 0.f};

    STAGE(0, 0, 0);
    __syncthreads();   // implicit vmcnt(0) drain: buf0 ready

    for (int s = 0; s < NSTEPS; ++s) {
        if (s + 1 < NSTEPS) {
            // uniform offsets: tile*65536 halfs (B panel step), d0 within row
            STAGE((s + 1) & 1, ((s + 1) >> 3) << 16, ((s + 1) & 7) * BKD);
        }
#pragma unroll
        for (int kh = 0; kh < 2; ++kh) {
            half8 af[4], bf[4];
#pragma unroll
            for (int i = 0; i < 4; ++i)
                af[i] = *(const half8*)(smemb + aaddr[kh][i]);
#pragma unroll
            for (int j = 0; j < 4; ++j)
                bf[j] = *(const half8*)(smemb + baddr[kh][j]);
#pragma unroll
            for (int i = 0; i < 4; ++i)
#pragma unroll
                for (int j = 0; j < 4; ++j)
                    acc[i][j] = __builtin_amdgcn_mfma_f32_16x16x32_f16(
                        af[i], bf[j], acc[i][j], 0, 0, 0);
        }
        if ((s & 7) == 7) {
            // tile done: fold scores into per-lane top-2, reset acc
            const int col0 = colBase + (s >> 3) * BC;
#pragma unroll
            for (int j = 0; j < 4; ++j) {
                int col = col0 + colHalf * 64 + j * 16 + l15;
                float cn = cnorm[col];
#pragma unroll
                for (int i = 0; i < 4; ++i) {
#pragma unroll
                    for (int r = 0; r < 4; ++r) {
                        float sc = fmaf(-2.0f, acc[i][j][r], cn);
                        int slot = i * 4 + r;
                        if (sc < b1[slot]) { b2[slot] = b1[slot]; b1[slot] = sc; i1[slot] = col; }
                        else if (sc < b2[slot]) b2[slot] = sc;
                    }
                }
            }
#pragma unroll
            for (int i = 0; i < 4; ++i)
#pragma unroll
                for (int j = 0; j < 4; ++j)
                    acc[i][j] = (floatx4){0.f, 0.f, 0.f, 0.f};
        }
        // toggle LDS read buffer (16 v_xor instead of full addr recompute)
#pragma unroll
        for (int kh = 0; kh < 2; ++kh)
#pragma unroll
            for (int i = 0; i < 4; ++i) { aaddr[kh][i] ^= 32768; baddr[kh][i] ^= 32768; }
        __syncthreads();   // drains s+1 loads; all waves done reading buf
    }
#undef STAGE

    // butterfly merge across the 16 col-lanes sharing each row
#pragma unroll
    for (int m = 1; m < 16; m <<= 1) {
#pragma unroll
        for (int s = 0; s < 16; ++s) {
            float ob1 = __shfl_xor(b1[s], m, 64);
            float ob2 = __shfl_xor(b2[s], m, 64);
            int   oi1 = __shfl_xor(i1[s], m, 64);
            if (ob1 < b1[s] || (ob1 == b1[s] && oi1 < i1[s])) {
                b2[s] = fminf(b1[s], ob2);
                b1[s] = ob1; i1[s] = oi1;
            } else {
                b2[s] = fminf(b2[s], ob1);
            }
        }
    }

    // reuse smem for cross-wave merge (all waves are past the final barrier)
    float* mb1 = (float*)smem;           // [2 colHalf][128 rows]
    float* mb2 = mb1 + 256;
    int*   mi1 = (int*)(mb2 + 256);
    if (l15 == 0) {
#pragma unroll
        for (int s = 0; s < 16; ++s) {
            int row = rowHalf * 64 + (s >> 2) * 16 + quad * 4 + (s & 3);
            mb1[colHalf * 128 + row] = b1[s];
            mb2[colHalf * 128 + row] = b2[s];
            mi1[colHalf * 128 + row] = i1[s];
        }
    }
    __syncthreads();
    if (tid < 128) {
        float a1 = mb1[tid], a2 = mb2[tid]; int ai = mi1[tid];
        float c1 = mb1[128 + tid], c2 = mb2[128 + tid]; int ci = mi1[128 + tid];
        float r1, r2; int ri;
        if (c1 < a1 || (c1 == a1 && ci < ai)) { r1 = c1; ri = ci; r2 = fminf(a1, c2); }
        else { r1 = a1; ri = ai; r2 = fminf(a2, c1); }
        size_t o = (size_t)by * N_TOT + row0 + tid;
        sb1[o] = r1; si1[o] = ri; sb2[o] = r2;
    }
}

// ---------------- merge K-splits, emit index + compact flagged-row list ----------------
__global__ __launch_bounds__(256) void merge_kernel(
    const float* __restrict__ sb1, const int* __restrict__ si1, const float* __restrict__ sb2,
    int* __restrict__ indices, int* __restrict__ flags,
    int* __restrict__ list, int* __restrict__ count,
    unsigned long long* __restrict__ result) {
    int n = blockIdx.x * 256 + threadIdx.x;
    float b1 = sb1[n]; int i1 = si1[n]; float b2 = sb2[n];
#pragma unroll
    for (int s = 1; s < NSPLIT; ++s) {
        float ob1 = sb1[(size_t)s * N_TOT + n];
        int   oi1 = si1[(size_t)s * N_TOT + n];
        float ob2 = sb2[(size_t)s * N_TOT + n];
        if (ob1 < b1 || (ob1 == b1 && oi1 < i1)) { b2 = fminf(b1, ob2); b1 = ob1; i1 = oi1; }
        else b2 = fminf(b2, ob1);
    }
    indices[n] = i1;
    result[n] = 0xFFFFFFFFFFFFFFFFull;
    int f = (b2 - b1 < MARGIN) ? 1 : 0;
    flags[n] = f;
    if (f) { int pos = atomicAdd(count, 1); list[pos] = n; }
}

// ---------------- batched exact fp32 rescan for flagged rows ----------------
// 32 flagged rows staged in LDS per batch; each thread owns ONE codebook row
// (32 parts x 256 rows) and streams it once against all 32 x-rows.
// Per-(n,k) score uses the EXACT fmaf order + final combine of the verified
// repair kernel -> bit-identical scores.
__global__ __launch_bounds__(256) void repair3_kernel(
    const float* __restrict__ x, const float* __restrict__ cb,
    const float* __restrict__ cnorm, const int* __restrict__ list,
    const int* __restrict__ count, unsigned long long* __restrict__ result) {
    __shared__ __align__(16) float xs[RB3][512];        // 64 KiB
    __shared__ unsigned long long red[RB3][4];
    const int tid = threadIdx.x;
    const int lane = tid & 63;
    const int wv = tid >> 6;
    const int part = blockIdx.x & (RP3 - 1);
    const int slot0 = blockIdx.x >> 5;                  // / RP3
    const int cnt = *count;
    const int nbatch = (cnt + RB3 - 1) / RB3;
    const int k = part * 256 + tid;                     // this thread's codebook row
    const float cn = cnorm[k];
    const float* crow = cb + (size_t)k * 512;

    for (int batch = slot0; batch < nbatch; batch += RSLOTS) {
        const int rb = min(RB3, cnt - batch * RB3);
        __syncthreads();   // previous iter's xs/red reads done
        for (int t = tid; t < rb * 128; t += 256) {
            int b = t >> 7, d4 = t & 127;
            int n = list[batch * RB3 + b];
            ((float4*)xs[b])[d4] = ((const float4*)(x + ((size_t)n << 9)))[d4];
        }
        __syncthreads();

        float d0[RB3], d1[RB3], d2[RB3], d3[RB3];
#pragma unroll
        for (int b = 0; b < RB3; ++b) { d0[b] = 0.f; d1[b] = 0.f; d2[b] = 0.f; d3[b] = 0.f; }

        for (int t = 0; t < 512; t += 16) {
            float4 c0 = *(const float4*)(crow + t);
            float4 c1 = *(const float4*)(crow + t + 4);
            float4 c2 = *(const float4*)(crow + t + 8);
            float4 c3 = *(const float4*)(crow + t + 12);
#pragma unroll
            for (int b = 0; b < RB3; ++b) {
                float4 x0 = *(const float4*)&xs[b][t];       // wave-uniform addr: LDS broadcast
                float4 x1 = *(const float4*)&xs[b][t + 4];
                float4 x2 = *(const float4*)&xs[b][t + 8];
                float4 x3 = *(const float4*)&xs[b][t + 12];
                d0[b] = fmaf(c0.x, x0.x, d0[b]);  d0[b] = fmaf(c0.y, x0.y, d0[b]);
                d0[b] = fmaf(c0.z, x0.z, d0[b]);  d0[b] = fmaf(c0.w, x0.w, d0[b]);
                d1[b] = fmaf(c1.x, x1.x, d1[b]);  d1[b] = fmaf(c1.y, x1.y, d1[b]);
                d1[b] = fmaf(c1.z, x1.z, d1[b]);  d1[b] = fmaf(c1.w, x1.w, d1[b]);
                d2[b] = fmaf(c2.x, x2.x, d2[b]);  d2[b] = fmaf(c2.y, x2.y, d2[b]);
                d2[b] = fmaf(c2.z, x2.z, d2[b]);  d2[b] = fmaf(c2.w, x2.w, d2[b]);
                d3[b] = fmaf(c3.x, x3.x, d3[b]);  d3[b] = fmaf(c3.y, x3.y, d3[b]);
                d3[b] = fmaf(c3.z, x3.z, d3[b]);  d3[b] = fmaf(c3.w, x3.w, d3[b]);
            }
        }

        // pack (ordered score bits, index): u64 min == (min score, then min index)
#pragma unroll
        for (int b = 0; b < RB3; ++b) {
            float s = cn - 2.f * ((d0[b] + d1[b]) + (d2[b] + d3[b]));
            unsigned int sb = __float_as_uint(s);
            sb = (sb & 0x80000000u) ? ~sb : (sb | 0x80000000u);
            unsigned long long p = ((unsigned long long)sb << 32) | (unsigned int)k;
#pragma unroll
            for (int m = 32; m > 0; m >>= 1) {
                unsigned long long o = shfl_xor_u64(p, m);
                if (o < p) p = o;
            }
            if (lane == 0) red[b][wv] = p;
        }
        __syncthreads();
        if (tid < RB3) {
            unsigned long long p = red[tid][0];
            if (red[tid][1] < p) p = red[tid][1];
            if (red[tid][2] < p) p = red[tid][2];
            if (red[tid][3] < p) p = red[tid][3];
            if (tid < rb) {
                int n = list[batch * RB3 + tid];
                atomicMin(&result[n], p);
            }
        }
    }
}

// ---------------- apply repaired indices ----------------
__global__ __launch_bounds__(256) void fixup_kernel(
    const int* __restrict__ flags, const unsigned long long* __restrict__ result,
    int* __restrict__ indices) {
    int n = blockIdx.x * 256 + threadIdx.x;
    if (flags[n]) indices[n] = (int)(result[n] & 0xFFFFFFFFu);
}

// ---------------- fallback fp32 argmin (used only if ws too small) ----------------
__global__ void cnorm_kernel(const float* __restrict__ cb, float* __restrict__ cnorm) {
    int wave = (blockIdx.x * blockDim.x + threadIdx.x) >> 6;
    int lane = threadIdx.x & 63;
    if (wave >= KCB) return;
    const float* row = cb + (size_t)wave * DDIM;
    float s = 0.f;
#pragma unroll
    for (int j = 0; j < DDIM / 64; ++j) { float v = row[lane + 64 * j]; s += v * v; }
#pragma unroll
    for (int off = 32; off > 0; off >>= 1) s += __shfl_down(s, off, 64);
    if (lane == 0) cnorm[wave] = s;
}

#define FBN 64
#define FBD 32
#define FLDA (FBN + 4)
__global__ __launch_bounds__(256) void argmin_fp32_kernel(
    const float* __restrict__ x, const float* __restrict__ cb,
    const float* __restrict__ cnorm, int* __restrict__ indices) {
    __shared__ float As[FBD][FLDA];
    __shared__ float Bs[FBD][FLDA];
    __shared__ float redv[FBN][16];
    __shared__ int   redi[FBN][16];
    const int tid = threadIdx.x;
    const int tx = tid & 15, ty = tid >> 4;
    const int row0 = blockIdx.x * FBN;
    float best[4]; int bidx[4];
#pragma unroll
    for (int i = 0; i < 4; ++i) { best[i] = 3.402823466e+38f; bidx[i] = KCB; }
    for (int k0 = 0; k0 < KCB; k0 += 64) {
        float acc[4][4] = {};
        for (int d0 = 0; d0 < DDIM; d0 += FBD) {
#pragma unroll
            for (int t = 0; t < 2; ++t) {
                int q = tid + t * 256, rr = q >> 3, dq = q & 7;
                float4 v = *(const float4*)(x + (size_t)(row0 + rr) * DDIM + d0 + dq * 4);
                As[dq*4+0][rr] = v.x; As[dq*4+1][rr] = v.y; As[dq*4+2][rr] = v.z; As[dq*4+3][rr] = v.w;
                float4 w = *(const float4*)(cb + (size_t)(k0 + rr) * DDIM + d0 + dq * 4);
                Bs[dq*4+0][rr] = w.x; Bs[dq*4+1][rr] = w.y; Bs[dq*4+2][rr] = w.z; Bs[dq*4+3][rr] = w.w;
            }
            __syncthreads();
#pragma unroll
            for (int d = 0; d < FBD; ++d) {
                float4 av = *(const float4*)&As[d][ty * 4];
                float4 bv = *(const float4*)&Bs[d][tx * 4];
                float a[4] = {av.x, av.y, av.z, av.w}, b[4] = {bv.x, bv.y, bv.z, bv.w};
#pragma unroll
                for (int i = 0; i < 4; ++i)
#pragma unroll
                    for (int j = 0; j < 4; ++j) acc[i][j] += a[i] * b[j];
            }
            __syncthreads();
        }
#pragma unroll
        for (int j = 0; j < 4; ++j) {
            int k = k0 + tx * 4 + j;
            float cn = cnorm[k];
#pragma unroll
            for (int i = 0; i < 4; ++i) {
                float s = cn - 2.0f * acc[i][j];
                if (s < best[i] || (s == best[i] && k < bidx[i])) { best[i] = s; bidx[i] = k; }
            }
        }
    }
#pragma unroll
    for (int i = 0; i < 4; ++i) { redv[ty*4+i][tx] = best[i]; redi[ty*4+i][tx] = bidx[i]; }
    __syncthreads();
    if (tid < FBN) {
        float bv = redv[tid][0]; int bi = redi[tid][0];
#pragma unroll
        for (int t = 1; t < 16; ++t) {
            float v = redv[tid][t]; int ii = redi[tid][t];
            if (v < bv || (v == bv && ii < bi)) { bv = v; bi = ii; }
        }
        indices[row0 + tid] = bi;
    }
}

// ---------------- gather + straight-through output + loss ----------------
__global__ __launch_bounds__(256) void output_kernel(
    const float* __restrict__ x, const float* __restrict__ cb,
    const int* __restrict__ indices, float* __restrict__ out,
    float* __restrict__ loss_acc) {
    size_t base = ((size_t)blockIdx.x * blockDim.x + threadIdx.x) * 16;
    int n = (int)(base >> 9);
    int d = (int)(base & 511);
    int idx = indices[n];
    const float* cr = cb + (size_t)idx * DDIM + d;
    const float* xr = x + base;
    float* orow = out + base;
    float lsum = 0.f;
#pragma unroll
    for (int t = 0; t < 4; ++t) {
        float4 q  = *(const float4*)(cr + t * 4);
        float4 xv = *(const float4*)(xr + t * 4);
        float dx0 = q.x - xv.x, dx1 = q.y - xv.y, dx2 = q.z - xv.z, dx3 = q.w - xv.w;
        float4 o;
        o.x = xv.x + dx0; o.y = xv.y + dx1; o.z = xv.z + dx2; o.w = xv.w + dx3;
        *(float4*)(orow + t * 4) = o;
        lsum += dx0*dx0 + dx1*dx1 + dx2*dx2 + dx3*dx3;
    }
#pragma unroll
    for (int off = 32; off > 0; off >>= 1) lsum += __shfl_down(lsum, off, 64);
    __shared__ float wsum[4];
    int lane = threadIdx.x & 63, wv = threadIdx.x >> 6;
    if (lane == 0) wsum[wv] = lsum;
    __syncthreads();
    if (threadIdx.x == 0) atomicAdd(loss_acc, wsum[0] + wsum[1] + wsum[2] + wsum[3]);
}

__global__ void finalize_kernel(const float* __restrict__ loss_acc, float* __restrict__ out_loss) {
    *out_loss = (*loss_acc) * (0.25f / (float)((size_t)N_TOT * DDIM));
}

extern "C" void kernel_launch(void* const* d_in, const int* in_sizes, int n_in,
                              void* d_out, int out_size, void* d_ws, size_t ws_size,
                              hipStream_t stream) {
    const float* x  = (const float*)d_in[0];
    const float* cb = (const float*)d_in[1];
    float* out = (float*)d_out;

    char* ws = (char*)d_ws;
    float* loss_acc = (float*)ws;                                 // 4 B
    int*   count    = (int*)(ws + 8);                             // 4 B
    int*   indices  = (int*)(ws + 256);                           // 128 KiB
    int*   flags    = (int*)(ws + 256 + 131072);                  // 128 KiB
    float* cnorm    = (float*)(ws + 256 + 2 * 131072);            // 32 KiB
    int*   list     = (int*)(ws + 256 + 2 * 131072 + 32768);      // 128 KiB
    unsigned long long* result =
        (unsigned long long*)(ws + 256 + 3 * 131072 + 32768);     // 256 KiB
    size_t off = 256 + 3 * 131072 + 32768 + 262144;               // ~0.69 MiB, 256-aligned
    _Float16* xh  = (_Float16*)(ws + off);                        // 32 MiB
    _Float16* cbh = (_Float16*)(ws + off + (size_t)N_TOT * DDIM * 2);  // 8 MiB
    size_t soff = off + (size_t)N_TOT * DDIM * 2 + (size_t)KCB * DDIM * 2;
    float* sb1 = (float*)(ws + soff);
    int*   si1 = (int*)(ws + soff + (size_t)NSPLIT * N_TOT * 4);
    float* sb2 = (float*)(ws + soff + (size_t)NSPLIT * N_TOT * 8);
    size_t need = soff + (size_t)NSPLIT * N_TOT * 12;

    hipMemsetAsync(ws, 0, 16, stream);   // loss_acc + count
    if (ws_size >= need) {
        convert_x_kernel<<<(N_TOT * DDIM) / (256 * 8), 256, 0, stream>>>(x, xh);
        convert_cb_kernel<<<KCB / 4, 256, 0, stream>>>(cb, cbh, cnorm);
        gemm_argmin_kernel<<<(N_TOT / BN) * NSPLIT, 256, 0, stream>>>(
            xh, cbh, cnorm, sb1, si1, sb2);
        merge_kernel<<<N_TOT / 256, 256, 0, stream>>>(sb1, si1, sb2, indices, flags,
                                                      list, count, result);
        repair3_kernel<<<RGRID3, 256, 0, stream>>>(x, cb, cnorm, list, count, result);
        fixup_kernel<<<N_TOT / 256, 256, 0, stream>>>(flags, result, indices);
    } else {
        cnorm_kernel<<<KCB / 4, 256, 0, stream>>>(cb, cnorm);
        argmin_fp32_kernel<<<N_TOT / FBN, 256, 0, stream>>>(x, cb, cnorm, indices);
    }
    output_kernel<<<((size_t)N_TOT * DDIM) / (256 * 16), 256, 0, stream>>>(
        x, cb, indices, out, loss_acc);
    finalize_kernel<<<1, 1, 0, stream>>>(loss_acc, out + (size_t)N_TOT * DDIM);
}

// Round 6
// 821.349 us; speedup vs baseline: 1.1104x; 1.1104x over previous
//
#include <hip/hip_runtime.h>
#include <stdint.h>

#define N_TOT 32768
#define DDIM  512
#define KCB   8192
#define NSPLIT 4
#define COLS_SPLIT (KCB / NSPLIT)   // 2048
#define BN 256                      // rows per block
#define BC 256                      // cols per block
#define BKD 64                      // d-chunk depth in halfs
#define NTILES (COLS_SPLIT / BC)    // 8
#define NSTEPS (NTILES * 8)         // 64 flattened (tile, d0) steps
#define MARGIN 0.15f

// batched repair: 32 flagged rows share one codebook stream
#define RB3 32                      // flagged rows per batch (LDS-staged)
#define RP3 32                      // codebook parts (256 rows each, 1 row/thread)
#define RSLOTS (RGRID3 / RP3)       // batch slots in flight
#define RGRID3 2048

typedef _Float16 half8 __attribute__((ext_vector_type(8)));
typedef float    floatx4 __attribute__((ext_vector_type(4)));

// ---------------- async global->LDS 16B ----------------
typedef const __attribute__((address_space(1))) unsigned int* gas_ptr;
typedef __attribute__((address_space(3))) unsigned int* las_ptr;
__device__ __forceinline__ void gld_lds16(void* l, const void* g) {
    __builtin_amdgcn_global_load_lds((gas_ptr)g, (las_ptr)l, 16, 0, 0);
}

__device__ __forceinline__ unsigned long long shfl_xor_u64(unsigned long long v, int m) {
    unsigned int lo = (unsigned int)v, hi = (unsigned int)(v >> 32);
    lo = __shfl_xor(lo, m, 64);
    hi = __shfl_xor(hi, m, 64);
    return ((unsigned long long)hi << 32) | lo;
}

// ---------------- convert x to fp16 ----------------
__global__ __launch_bounds__(256) void convert_x_kernel(
    const float* __restrict__ x, _Float16* __restrict__ xh) {
    size_t i = ((size_t)blockIdx.x * 256 + threadIdx.x) * 8;
    float4 v0 = *(const float4*)(x + i);
    float4 v1 = *(const float4*)(x + i + 4);
    half8 h;
    h[0] = (_Float16)v0.x; h[1] = (_Float16)v0.y; h[2] = (_Float16)v0.z; h[3] = (_Float16)v0.w;
    h[4] = (_Float16)v1.x; h[5] = (_Float16)v1.y; h[6] = (_Float16)v1.z; h[7] = (_Float16)v1.w;
    *(half8*)(xh + i) = h;
}

// ---------------- convert codebook to fp16 + fp32 norms (one wave/row) ----------------
__global__ __launch_bounds__(256) void convert_cb_kernel(
    const float* __restrict__ cb, _Float16* __restrict__ cbh, float* __restrict__ cnorm) {
    int row = blockIdx.x * 4 + (threadIdx.x >> 6);
    int lane = threadIdx.x & 63;
    const float* src = cb + (size_t)row * DDIM + lane * 8;
    float4 v0 = *(const float4*)src;
    float4 v1 = *(const float4*)(src + 4);
    half8 h;
    h[0] = (_Float16)v0.x; h[1] = (_Float16)v0.y; h[2] = (_Float16)v0.z; h[3] = (_Float16)v0.w;
    h[4] = (_Float16)v1.x; h[5] = (_Float16)v1.y; h[6] = (_Float16)v1.z; h[7] = (_Float16)v1.w;
    *(half8*)(cbh + (size_t)row * DDIM + lane * 8) = h;
    float s = v0.x*v0.x + v0.y*v0.y + v0.z*v0.z + v0.w*v0.w
            + v1.x*v1.x + v1.y*v1.y + v1.z*v1.z + v1.w*v1.w;
#pragma unroll
    for (int off = 32; off > 0; off >>= 1) s += __shfl_down(s, off, 64);
    if (lane == 0) cnorm[row] = s;
}

// ---------------- fused fp16 MFMA GEMM + per-row top-2 argmin (K-split) ----------------
// 256x256 block tile, 8 waves (wave-tile 64 rows x 128 cols): 131 FLOP per LDS-staged
// byte (2x the 128x128 tile) -> halves the staging traffic that bounds this kernel.
// Double-buffered single-barrier pipeline; chunk-XOR-swizzled LDS (conflict-free).
__global__ __launch_bounds__(512, 2) void gemm_argmin_kernel(
    const _Float16* __restrict__ xh, const _Float16* __restrict__ cbh,
    const float* __restrict__ cnorm,
    float* __restrict__ sb1, int* __restrict__ si1, float* __restrict__ sb2) {

    __shared__ __align__(16) _Float16 smem[65536];  // 128 KiB: 2 x (A[256][64] + B[256][64])
    char* smemb = (char*)smem;

    const int tid = threadIdx.x;
    const int wave = tid >> 6;        // 0..7
    const int lane = tid & 63;
    const int rowPart = wave >> 1;    // 0..3 (64-row strip)
    const int colPart = wave & 1;     // 0..1 (128-col strip)
    const int l15 = lane & 15;
    const int quad = lane >> 4;

    // bijective XCD swizzle (512 blocks, 512 % 8 == 0): XCD k -> contiguous 64 wg
    const int orig = blockIdx.x;
    const int wg = (orig & 7) * 64 + (orig >> 3);
    const int bx = wg & 127;
    const int by = wg >> 7;
    const int row0 = bx * BN;
    const int colBase = by * COLS_SPLIT;

    // ---- step-invariant per-lane staging offsets (halfs) ----
    int voff[4];
#pragma unroll
    for (int r = 0; r < 4; ++r) {
        int c = wave * 256 + r * 64 + lane;   // 0..2047 chunk-slot
        int ar = c >> 3;                      // 0..255 row
        int q  = (c & 7) ^ (ar & 7);          // XOR swizzle: conflict-free frag reads
        voff[r] = (ar << 9) + q * 8;
    }
    const _Float16* aptr = xh + ((size_t)row0 << 9);      // wave-uniform base
    const _Float16* bptr = cbh + ((size_t)colBase << 9);  // wave-uniform base

    // ---- step-invariant swizzled LDS read byte-addresses (par=0, kh=0) ----
    // kh=1 is ^64 (chunk-bit2 <-> byte-bit6); par=1 is +65536.
    int aaddr[4], baddr[8];
#pragma unroll
    for (int i = 0; i < 4; ++i) {
        int rr = rowPart * 64 + i * 16 + l15;
        int qa = quad ^ (rr & 7);
        aaddr[i] = rr * 128 + qa * 16;
    }
#pragma unroll
    for (int j = 0; j < 8; ++j) {
        int cc = colPart * 128 + j * 16 + l15;
        int qb = quad ^ (cc & 7);
        baddr[j] = 32768 + cc * 128 + qb * 16;
    }

    float b1[16], b2[16];
    int   i1[16];
#pragma unroll
    for (int s = 0; s < 16; ++s) { b1[s] = 3.402823466e38f; b2[s] = 3.402823466e38f; i1[s] = 0; }

#define STAGE(parv, boffu, d0v) do {                                            \
        _Float16* Asb = smem + (parv) * 32768;                                  \
        _Float16* Bsb = Asb + 16384;                                            \
        _Pragma("unroll")                                                       \
        for (int r = 0; r < 4; ++r) {                                           \
            gld_lds16(Asb + (wave * 256 + r * 64) * 8,                          \
                      aptr + (d0v) + voff[r]);                                  \
            gld_lds16(Bsb + (wave * 256 + r * 64) * 8,                          \
                      bptr + (boffu) + (d0v) + voff[r]);                        \
        }                                                                       \
    } while (0)

    floatx4 acc[4][8];
#pragma unroll
    for (int i = 0; i < 4; ++i)
#pragma unroll
        for (int j = 0; j < 8; ++j)
            acc[i][j] = (floatx4){0.f, 0.f, 0.f, 0.f};

    STAGE(0, 0, 0);
    __syncthreads();   // implicit vmcnt(0) drain: buf0 ready

    int pofs = 0;      // current read-buffer byte offset (0 / 65536)
    for (int s = 0; s < NSTEPS; ++s) {
        if (s + 1 < NSTEPS) {
            // B panel step per tile = 256 rows * 512 halfs = 1<<17
            STAGE((s + 1) & 1, ((s + 1) >> 3) << 17, ((s + 1) & 7) * BKD);
        }
#pragma unroll
        for (int kh = 0; kh < 2; ++kh) {
            half8 af[4], bf[8];
#pragma unroll
            for (int i = 0; i < 4; ++i)
                af[i] = *(const half8*)(smemb + (pofs + (aaddr[i] ^ (kh << 6))));
#pragma unroll
            for (int j = 0; j < 8; ++j)
                bf[j] = *(const half8*)(smemb + (pofs + (baddr[j] ^ (kh << 6))));
#pragma unroll
            for (int i = 0; i < 4; ++i)
#pragma unroll
                for (int j = 0; j < 8; ++j)
                    acc[i][j] = __builtin_amdgcn_mfma_f32_16x16x32_f16(
                        af[i], bf[j], acc[i][j], 0, 0, 0);
        }
        if ((s & 7) == 7) {
            // tile done: fold scores into per-lane top-2, reset acc
            const int col0 = colBase + (s >> 3) * BC;
#pragma unroll
            for (int j = 0; j < 8; ++j) {
                int col = col0 + colPart * 128 + j * 16 + l15;
                float cn = cnorm[col];
#pragma unroll
                for (int i = 0; i < 4; ++i) {
#pragma unroll
                    for (int r = 0; r < 4; ++r) {
                        float sc = fmaf(-2.0f, acc[i][j][r], cn);
                        int slot = i * 4 + r;
                        if (sc < b1[slot]) { b2[slot] = b1[slot]; b1[slot] = sc; i1[slot] = col; }
                        else if (sc < b2[slot]) b2[slot] = sc;
                    }
                }
            }
#pragma unroll
            for (int i = 0; i < 4; ++i)
#pragma unroll
                for (int j = 0; j < 8; ++j)
                    acc[i][j] = (floatx4){0.f, 0.f, 0.f, 0.f};
        }
        pofs ^= 65536;
        __syncthreads();   // drains s+1 loads; all waves done reading old buf
    }
#undef STAGE

    // butterfly merge across the 16 col-lanes sharing each row
#pragma unroll
    for (int m = 1; m < 16; m <<= 1) {
#pragma unroll
        for (int s = 0; s < 16; ++s) {
            float ob1 = __shfl_xor(b1[s], m, 64);
            float ob2 = __shfl_xor(b2[s], m, 64);
            int   oi1 = __shfl_xor(i1[s], m, 64);
            if (ob1 < b1[s] || (ob1 == b1[s] && oi1 < i1[s])) {
                b2[s] = fminf(b1[s], ob2);
                b1[s] = ob1; i1[s] = oi1;
            } else {
                b2[s] = fminf(b2[s], ob1);
            }
        }
    }

    // reuse smem for cross-wave merge (all waves are past the final barrier)
    float* mb1 = (float*)smem;           // [2 colPart][256 rows]
    float* mb2 = mb1 + 512;
    int*   mi1 = (int*)(mb2 + 512);
    if (l15 == 0) {
#pragma unroll
        for (int s = 0; s < 16; ++s) {
            int row = rowPart * 64 + (s >> 2) * 16 + quad * 4 + (s & 3);
            mb1[colPart * 256 + row] = b1[s];
            mb2[colPart * 256 + row] = b2[s];
            mi1[colPart * 256 + row] = i1[s];
        }
    }
    __syncthreads();
    if (tid < 256) {
        float a1 = mb1[tid], a2 = mb2[tid]; int ai = mi1[tid];
        float c1 = mb1[256 + tid], c2 = mb2[256 + tid]; int ci = mi1[256 + tid];
        float r1, r2; int ri;
        if (c1 < a1 || (c1 == a1 && ci < ai)) { r1 = c1; ri = ci; r2 = fminf(a1, c2); }
        else { r1 = a1; ri = ai; r2 = fminf(a2, c1); }
        size_t o = (size_t)by * N_TOT + row0 + tid;
        sb1[o] = r1; si1[o] = ri; sb2[o] = r2;
    }
}

// ---------------- merge K-splits, emit index + compact flagged-row list ----------------
__global__ __launch_bounds__(256) void merge_kernel(
    const float* __restrict__ sb1, const int* __restrict__ si1, const float* __restrict__ sb2,
    int* __restrict__ indices, int* __restrict__ flags,
    int* __restrict__ list, int* __restrict__ count,
    unsigned long long* __restrict__ result) {
    int n = blockIdx.x * 256 + threadIdx.x;
    float b1 = sb1[n]; int i1 = si1[n]; float b2 = sb2[n];
#pragma unroll
    for (int s = 1; s < NSPLIT; ++s) {
        float ob1 = sb1[(size_t)s * N_TOT + n];
        int   oi1 = si1[(size_t)s * N_TOT + n];
        float ob2 = sb2[(size_t)s * N_TOT + n];
        if (ob1 < b1 || (ob1 == b1 && oi1 < i1)) { b2 = fminf(b1, ob2); b1 = ob1; i1 = oi1; }
        else b2 = fminf(b2, ob1);
    }
    indices[n] = i1;
    result[n] = 0xFFFFFFFFFFFFFFFFull;
    int f = (b2 - b1 < MARGIN) ? 1 : 0;
    flags[n] = f;
    if (f) { int pos = atomicAdd(count, 1); list[pos] = n; }
}

// ---------------- batched exact fp32 rescan for flagged rows ----------------
// 32 flagged rows staged in LDS per batch; each thread owns ONE codebook row
// (32 parts x 256 rows) and streams it once against all 32 x-rows.
// Per-(n,k) score uses the EXACT fmaf order + final combine of the verified
// repair kernel -> bit-identical scores.
__global__ __launch_bounds__(256) void repair3_kernel(
    const float* __restrict__ x, const float* __restrict__ cb,
    const float* __restrict__ cnorm, const int* __restrict__ list,
    const int* __restrict__ count, unsigned long long* __restrict__ result) {
    __shared__ __align__(16) float xs[RB3][512];        // 64 KiB
    __shared__ unsigned long long red[RB3][4];
    const int tid = threadIdx.x;
    const int lane = tid & 63;
    const int wv = tid >> 6;
    const int part = blockIdx.x & (RP3 - 1);
    const int slot0 = blockIdx.x >> 5;                  // / RP3
    const int cnt = *count;
    const int nbatch = (cnt + RB3 - 1) / RB3;
    const int k = part * 256 + tid;                     // this thread's codebook row
    const float cn = cnorm[k];
    const float* crow = cb + (size_t)k * 512;

    for (int batch = slot0; batch < nbatch; batch += RSLOTS) {
        const int rb = min(RB3, cnt - batch * RB3);
        __syncthreads();   // previous iter's xs/red reads done
        for (int t = tid; t < rb * 128; t += 256) {
            int b = t >> 7, d4 = t & 127;
            int n = list[batch * RB3 + b];
            ((float4*)xs[b])[d4] = ((const float4*)(x + ((size_t)n << 9)))[d4];
        }
        __syncthreads();

        float d0[RB3], d1[RB3], d2[RB3], d3[RB3];
#pragma unroll
        for (int b = 0; b < RB3; ++b) { d0[b] = 0.f; d1[b] = 0.f; d2[b] = 0.f; d3[b] = 0.f; }

        for (int t = 0; t < 512; t += 16) {
            float4 c0 = *(const float4*)(crow + t);
            float4 c1 = *(const float4*)(crow + t + 4);
            float4 c2 = *(const float4*)(crow + t + 8);
            float4 c3 = *(const float4*)(crow + t + 12);
#pragma unroll
            for (int b = 0; b < RB3; ++b) {
                float4 x0 = *(const float4*)&xs[b][t];       // wave-uniform addr: LDS broadcast
                float4 x1 = *(const float4*)&xs[b][t + 4];
                float4 x2 = *(const float4*)&xs[b][t + 8];
                float4 x3 = *(const float4*)&xs[b][t + 12];
                d0[b] = fmaf(c0.x, x0.x, d0[b]);  d0[b] = fmaf(c0.y, x0.y, d0[b]);
                d0[b] = fmaf(c0.z, x0.z, d0[b]);  d0[b] = fmaf(c0.w, x0.w, d0[b]);
                d1[b] = fmaf(c1.x, x1.x, d1[b]);  d1[b] = fmaf(c1.y, x1.y, d1[b]);
                d1[b] = fmaf(c1.z, x1.z, d1[b]);  d1[b] = fmaf(c1.w, x1.w, d1[b]);
                d2[b] = fmaf(c2.x, x2.x, d2[b]);  d2[b] = fmaf(c2.y, x2.y, d2[b]);
                d2[b] = fmaf(c2.z, x2.z, d2[b]);  d2[b] = fmaf(c2.w, x2.w, d2[b]);
                d3[b] = fmaf(c3.x, x3.x, d3[b]);  d3[b] = fmaf(c3.y, x3.y, d3[b]);
                d3[b] = fmaf(c3.z, x3.z, d3[b]);  d3[b] = fmaf(c3.w, x3.w, d3[b]);
            }
        }

        // pack (ordered score bits, index): u64 min == (min score, then min index)
#pragma unroll
        for (int b = 0; b < RB3; ++b) {
            float s = cn - 2.f * ((d0[b] + d1[b]) + (d2[b] + d3[b]));
            unsigned int sb = __float_as_uint(s);
            sb = (sb & 0x80000000u) ? ~sb : (sb | 0x80000000u);
            unsigned long long p = ((unsigned long long)sb << 32) | (unsigned int)k;
#pragma unroll
            for (int m = 32; m > 0; m >>= 1) {
                unsigned long long o = shfl_xor_u64(p, m);
                if (o < p) p = o;
            }
            if (lane == 0) red[b][wv] = p;
        }
        __syncthreads();
        if (tid < RB3) {
            unsigned long long p = red[tid][0];
            if (red[tid][1] < p) p = red[tid][1];
            if (red[tid][2] < p) p = red[tid][2];
            if (red[tid][3] < p) p = red[tid][3];
            if (tid < rb) {
                int n = list[batch * RB3 + tid];
                atomicMin(&result[n], p);
            }
        }
    }
}

// ---------------- apply repaired indices ----------------
__global__ __launch_bounds__(256) void fixup_kernel(
    const int* __restrict__ flags, const unsigned long long* __restrict__ result,
    int* __restrict__ indices) {
    int n = blockIdx.x * 256 + threadIdx.x;
    if (flags[n]) indices[n] = (int)(result[n] & 0xFFFFFFFFu);
}

// ---------------- fallback fp32 argmin (used only if ws too small) ----------------
__global__ void cnorm_kernel(const float* __restrict__ cb, float* __restrict__ cnorm) {
    int wave = (blockIdx.x * blockDim.x + threadIdx.x) >> 6;
    int lane = threadIdx.x & 63;
    if (wave >= KCB) return;
    const float* row = cb + (size_t)wave * DDIM;
    float s = 0.f;
#pragma unroll
    for (int j = 0; j < DDIM / 64; ++j) { float v = row[lane + 64 * j]; s += v * v; }
#pragma unroll
    for (int off = 32; off > 0; off >>= 1) s += __shfl_down(s, off, 64);
    if (lane == 0) cnorm[wave] = s;
}

#define FBN 64
#define FBD 32
#define FLDA (FBN + 4)
__global__ __launch_bounds__(256) void argmin_fp32_kernel(
    const float* __restrict__ x, const float* __restrict__ cb,
    const float* __restrict__ cnorm, int* __restrict__ indices) {
    __shared__ float As[FBD][FLDA];
    __shared__ float Bs[FBD][FLDA];
    __shared__ float redv[FBN][16];
    __shared__ int   redi[FBN][16];
    const int tid = threadIdx.x;
    const int tx = tid & 15, ty = tid >> 4;
    const int row0 = blockIdx.x * FBN;
    float best[4]; int bidx[4];
#pragma unroll
    for (int i = 0; i < 4; ++i) { best[i] = 3.402823466e+38f; bidx[i] = KCB; }
    for (int k0 = 0; k0 < KCB; k0 += 64) {
        float acc[4][4] = {};
        for (int d0 = 0; d0 < DDIM; d0 += FBD) {
#pragma unroll
            for (int t = 0; t < 2; ++t) {
                int q = tid + t * 256, rr = q >> 3, dq = q & 7;
                float4 v = *(const float4*)(x + (size_t)(row0 + rr) * DDIM + d0 + dq * 4);
                As[dq*4+0][rr] = v.x; As[dq*4+1][rr] = v.y; As[dq*4+2][rr] = v.z; As[dq*4+3][rr] = v.w;
                float4 w = *(const float4*)(cb + (size_t)(k0 + rr) * DDIM + d0 + dq * 4);
                Bs[dq*4+0][rr] = w.x; Bs[dq*4+1][rr] = w.y; Bs[dq*4+2][rr] = w.z; Bs[dq*4+3][rr] = w.w;
            }
            __syncthreads();
#pragma unroll
            for (int d = 0; d < FBD; ++d) {
                float4 av = *(const float4*)&As[d][ty * 4];
                float4 bv = *(const float4*)&Bs[d][tx * 4];
                float a[4] = {av.x, av.y, av.z, av.w}, b[4] = {bv.x, bv.y, bv.z, bv.w};
#pragma unroll
                for (int i = 0; i < 4; ++i)
#pragma unroll
                    for (int j = 0; j < 4; ++j) acc[i][j] += a[i] * b[j];
            }
            __syncthreads();
        }
#pragma unroll
        for (int j = 0; j < 4; ++j) {
            int k = k0 + tx * 4 + j;
            float cn = cnorm[k];
#pragma unroll
            for (int i = 0; i < 4; ++i) {
                float s = cn - 2.0f * acc[i][j];
                if (s < best[i] || (s == best[i] && k < bidx[i])) { best[i] = s; bidx[i] = k; }
            }
        }
    }
#pragma unroll
    for (int i = 0; i < 4; ++i) { redv[ty*4+i][tx] = best[i]; redi[ty*4+i][tx] = bidx[i]; }
    __syncthreads();
    if (tid < FBN) {
        float bv = redv[tid][0]; int bi = redi[tid][0];
#pragma unroll
        for (int t = 1; t < 16; ++t) {
            float v = redv[tid][t]; int ii = redi[tid][t];
            if (v < bv || (v == bv && ii < bi)) { bv = v; bi = ii; }
        }
        indices[row0 + tid] = bi;
    }
}

// ---------------- gather + straight-through output + loss ----------------
__global__ __launch_bounds__(256) void output_kernel(
    const float* __restrict__ x, const float* __restrict__ cb,
    const int* __restrict__ indices, float* __restrict__ out,
    float* __restrict__ loss_acc) {
    size_t base = ((size_t)blockIdx.x * blockDim.x + threadIdx.x) * 16;
    int n = (int)(base >> 9);
    int d = (int)(base & 511);
    int idx = indices[n];
    const float* cr = cb + (size_t)idx * DDIM + d;
    const float* xr = x + base;
    float* orow = out + base;
    float lsum = 0.f;
#pragma unroll
    for (int t = 0; t < 4; ++t) {
        float4 q  = *(const float4*)(cr + t * 4);
        float4 xv = *(const float4*)(xr + t * 4);
        float dx0 = q.x - xv.x, dx1 = q.y - xv.y, dx2 = q.z - xv.z, dx3 = q.w - xv.w;
        float4 o;
        o.x = xv.x + dx0; o.y = xv.y + dx1; o.z = xv.z + dx2; o.w = xv.w + dx3;
        *(float4*)(orow + t * 4) = o;
        lsum += dx0*dx0 + dx1*dx1 + dx2*dx2 + dx3*dx3;
    }
#pragma unroll
    for (int off = 32; off > 0; off >>= 1) lsum += __shfl_down(lsum, off, 64);
    __shared__ float wsum[4];
    int lane = threadIdx.x & 63, wv = threadIdx.x >> 6;
    if (lane == 0) wsum[wv] = lsum;
    __syncthreads();
    if (threadIdx.x == 0) atomicAdd(loss_acc, wsum[0] + wsum[1] + wsum[2] + wsum[3]);
}

__global__ void finalize_kernel(const float* __restrict__ loss_acc, float* __restrict__ out_loss) {
    *out_loss = (*loss_acc) * (0.25f / (float)((size_t)N_TOT * DDIM));
}

extern "C" void kernel_launch(void* const* d_in, const int* in_sizes, int n_in,
                              void* d_out, int out_size, void* d_ws, size_t ws_size,
                              hipStream_t stream) {
    const float* x  = (const float*)d_in[0];
    const float* cb = (const float*)d_in[1];
    float* out = (float*)d_out;

    char* ws = (char*)d_ws;
    float* loss_acc = (float*)ws;                                 // 4 B
    int*   count    = (int*)(ws + 8);                             // 4 B
    int*   indices  = (int*)(ws + 256);                           // 128 KiB
    int*   flags    = (int*)(ws + 256 + 131072);                  // 128 KiB
    float* cnorm    = (float*)(ws + 256 + 2 * 131072);            // 32 KiB
    int*   list     = (int*)(ws + 256 + 2 * 131072 + 32768);      // 128 KiB
    unsigned long long* result =
        (unsigned long long*)(ws + 256 + 3 * 131072 + 32768);     // 256 KiB
    size_t off = 256 + 3 * 131072 + 32768 + 262144;               // ~0.69 MiB, 256-aligned
    _Float16* xh  = (_Float16*)(ws + off);                        // 32 MiB
    _Float16* cbh = (_Float16*)(ws + off + (size_t)N_TOT * DDIM * 2);  // 8 MiB
    size_t soff = off + (size_t)N_TOT * DDIM * 2 + (size_t)KCB * DDIM * 2;
    float* sb1 = (float*)(ws + soff);
    int*   si1 = (int*)(ws + soff + (size_t)NSPLIT * N_TOT * 4);
    float* sb2 = (float*)(ws + soff + (size_t)NSPLIT * N_TOT * 8);
    size_t need = soff + (size_t)NSPLIT * N_TOT * 12;

    hipMemsetAsync(ws, 0, 16, stream);   // loss_acc + count
    if (ws_size >= need) {
        convert_x_kernel<<<(N_TOT * DDIM) / (256 * 8), 256, 0, stream>>>(x, xh);
        convert_cb_kernel<<<KCB / 4, 256, 0, stream>>>(cb, cbh, cnorm);
        gemm_argmin_kernel<<<(N_TOT / BN) * NSPLIT, 512, 0, stream>>>(
            xh, cbh, cnorm, sb1, si1, sb2);
        merge_kernel<<<N_TOT / 256, 256, 0, stream>>>(sb1, si1, sb2, indices, flags,
                                                      list, count, result);
        repair3_kernel<<<RGRID3, 256, 0, stream>>>(x, cb, cnorm, list, count, result);
        fixup_kernel<<<N_TOT / 256, 256, 0, stream>>>(flags, result, indices);
    } else {
        cnorm_kernel<<<KCB / 4, 256, 0, stream>>>(cb, cnorm);
        argmin_fp32_kernel<<<N_TOT / FBN, 256, 0, stream>>>(x, cb, cnorm, indices);
    }
    output_kernel<<<((size_t)N_TOT * DDIM) / (256 * 16), 256, 0, stream>>>(
        x, cb, indices, out, loss_acc);
    finalize_kernel<<<1, 1, 0, stream>>>(loss_acc, out + (size_t)N_TOT * DDIM);
}